// Round 8
// baseline (30.800 us; speedup 1.0000x reference)
//
#include <hip/hip_runtime.h>
#include <hip/hip_bf16.h>
#include <math.h>

#define IN_DIM   512
#define OUT_DIM  512
#define NK       192          // TOTAL_K
#define KF       384          // 2*TOTAL_K
#define XAVIER   0.04419417382415922f
#define BIAS_SCALE 0.02f

typedef __attribute__((ext_vector_type(8))) short bf16x8;
typedef __attribute__((ext_vector_type(4))) float f32x4;
typedef unsigned short u16;
typedef unsigned int   u32;
typedef unsigned long long u64;

__device__ inline u16 f2bf(float f) {
    __hip_bfloat16 h = __float2bfloat16(f);
    return *reinterpret_cast<u16*>(&h);
}
__device__ inline u32 pack2bf(float lo, float hi) {
    return (u32)f2bf(lo) | ((u32)f2bf(hi) << 16);
}
// Native-rate sincos (revolutions). |arg| < ~50 rad here; err ~1e-6 << bf16 W quant.
__device__ inline void fsincos(float x, float& s, float& c) {
    float t = x * 0.15915494309189535f;   // 1/(2*pi)
    t -= floorf(t);
    s = __builtin_amdgcn_sinf(t);
    c = __builtin_amdgcn_cosf(t);
}

// ---------------------------------------------------------------------------
// Kernel 1: synthesis — byte-identical to the verified 24.1us version.
// ---------------------------------------------------------------------------
__global__ __launch_bounds__(512) void synth_fused(
    const float* __restrict__ omega, const float* __restrict__ phi,
    const float* __restrict__ alpha, const float* __restrict__ alpha_bias,
    const int* __restrict__ layer_idx, const int* __restrict__ num_layers,
    u16* __restrict__ Wt, float* __restrict__ bias)
{
    const int b   = blockIdx.x;
    const int tid = threadIdx.x;
    const float l = ((float)layer_idx[0] + 1.0f) / ((float)num_layers[0] + 1.0f);

    __shared__ u16 sV[32 * KF];   // 24KB
    __shared__ u16 sU[32 * KF];   // 24KB
    __shared__ float bsc[4];

    const int bi = b & 15, bj = b >> 4;
    const int i0 = bi * 32, j0 = bj * 32;

    #pragma unroll 4
    for (int q = 0; q < 12; ++q) {
        const int e  = q * 512 + tid;     // 0..6143
        const int rl = e / NK;
        const int k  = e - rl * NK;
        const int swz  = (rl & 7) << 4;
        const int base = rl * (KF * 2);
        const float om0 = omega[3*k], om1 = omega[3*k+1], om2 = omega[3*k+2];
        const float ph  = phi[k];
        {
            const float ii = (i0 + rl + 1.0f) * (1.0f / (IN_DIM + 1.0f));
            float s, c; fsincos(fmaf(ii, om0, fmaf(l, om2, ph)), s, c);
            *(u16*)((char*)sU + base + (((2*k)      ) ^ swz)) = f2bf(s);
            *(u16*)((char*)sU + base + (((2*k) + 384) ^ swz)) = f2bf(c);
        }
        {
            const float jj = (j0 + rl + 1.0f) * (1.0f / (OUT_DIM + 1.0f));
            float sv, cv; fsincos(jj * om1, sv, cv);
            const float as = alpha[k], ac = alpha[NK + k];
            *(u16*)((char*)sV + base + (((2*k)      ) ^ swz)) = f2bf((as*cv - ac*sv) * XAVIER);
            *(u16*)((char*)sV + base + (((2*k) + 384) ^ swz)) = f2bf((ac*cv + as*sv) * XAVIER);
        }
    }

    // bias partials: waves 4..7 (k-parallel, 128 threads per output)
    if (tid >= 256) {
        const int t2 = tid - 256;
        const int g  = t2 >> 7;
        const int k0 = t2 & 127;
        const int j  = 2*b + g;
        const float jj = (j + 1.0f) * (1.0f / (OUT_DIM + 1.0f));
        float bp = 0.0f;
        {
            float s, c;
            fsincos(fmaf(jj, omega[3*k0+1], fmaf(l, omega[3*k0+2], phi[k0])), s, c);
            bp = fmaf(alpha_bias[k0], s, fmaf(alpha_bias[NK + k0], c, bp));
        }
        if (k0 < 64) {
            const int k = k0 + 128;
            float s, c;
            fsincos(fmaf(jj, omega[3*k+1], fmaf(l, omega[3*k+2], phi[k])), s, c);
            bp = fmaf(alpha_bias[k], s, fmaf(alpha_bias[NK + k], c, bp));
        }
        #pragma unroll
        for (int off = 32; off > 0; off >>= 1)
            bp += __shfl_down(bp, off);
        if ((tid & 63) == 0) bsc[t2 >> 6] = bp;
    }
    __syncthreads();

    // 32x32x384 tile GEMM (waves 0..3) -> Wt
    if (tid < 256) {
        const int wave = tid >> 6, lane = tid & 63;
        const int wr = wave >> 1, wc = wave & 1;
        f32x4 acc = {};
        #pragma unroll
        for (int kk = 0; kk < KF / 32; ++kk) {
            const int kb = kk * 64 + (lane >> 4) * 16;
            const int ra = wr*16 + (lane & 15);
            const int rb = wc*16 + (lane & 15);
            bf16x8 a = *reinterpret_cast<const bf16x8*>(
                (const char*)sV + ra*768 + (kb ^ ((ra & 7) << 4)));
            bf16x8 bb = *reinterpret_cast<const bf16x8*>(
                (const char*)sU + rb*768 + (kb ^ ((rb & 7) << 4)));
            acc = __builtin_amdgcn_mfma_f32_16x16x32_bf16(a, bb, acc, 0, 0, 0);
        }
        const int row = j0 + wr*16 + (lane >> 4) * 4;   // out col j
        const int col = i0 + wc*16 + (lane & 15);       // in row i
        #pragma unroll
        for (int r = 0; r < 4; ++r)
            Wt[(size_t)(row + r) * IN_DIM + col] = f2bf(acc[r]);
    }
    if (tid == 256) bias[2*b    ] = (bsc[0] + bsc[1]) * BIAS_SCALE;
    if (tid == 257) bias[2*b + 1] = (bsc[2] + bsc[3]) * BIAS_SCALE;
}

// ---------------------------------------------------------------------------
// Kernel 2 REDESIGN: per-wave register-double-buffered B, zero loop barriers.
// Facts driving this: (r1) wave w stages exactly the B-rows it alone reads ->
// block barriers only served the 4KB A tile; B's LDS hop is a per-lane
// identity. (r6) direct-global B without staging discipline = JIT loads,
// latency-serial. Here: A staged once to LDS (32KB, ONE barrier); B loaded
// straight to VGPRs, 3-slot rotating buffer, 2 half-steps of lookahead,
// counted vmcnt(4) per half-step; per-lane base pointers + literal offsets
// (h*64B) -> zero per-step address VALU. 8 waves free-run independently.
// ---------------------------------------------------------------------------
__global__ __launch_bounds__(512) void main_gemm(
    const float* __restrict__ X, const u16* __restrict__ Wt,
    const float* __restrict__ bias, float* __restrict__ out, int M)
{
    __shared__ u16 sA[32 * 512];      // 32KB: full A tile, bf16, swizzled rows

    const int tid  = threadIdx.x;
    const int w    = tid >> 6, lane = tid & 63;
    const int ll   = lane & 15, lh = lane >> 4;
    const int brow = blockIdx.x * 32;

    #define VMW4  asm volatile("s_waitcnt vmcnt(4)" ::: "memory")
    #define VMW0  asm volatile("s_waitcnt vmcnt(0)" ::: "memory")

    // per-lane B base pointers (n = 0..3); loop offset is h*64 bytes (imm)
    const u16* Bb[4];
    #pragma unroll
    for (int n = 0; n < 4; ++n)
        Bb[n] = Wt + (size_t)(w * 64 + n * 16 + ll) * IN_DIM + lh * 8;

    bf16x8 b[3][4];
    auto loadB = [&](int h, int slot) {
        #pragma unroll
        for (int n = 0; n < 4; ++n)
            b[slot][n] = *reinterpret_cast<const bf16x8*>(Bb[n] + h * 32);
    };

    // issue B(0), B(1) first: their latency hides under the A prologue
    loadB(0, 0);
    loadB(1, 1);
    asm volatile("" ::: "memory");

    // ---- A prologue: x (fp32, coalesced) -> sA (bf16, swz=(row&3)<<4) ---
    // weaker swizzle than r6 so the K-offset (h*64, bits>=6) never collides
    // with swizzle bits (4..5) -> folds into the ds_read literal offset.
    // Residual 2-way LDS read conflict is free (m136).
    {
        const int row = tid >> 4;         // 0..31
        const int q   = tid & 15;         // 16 threads per row
        const int swz = (row & 3) << 4;
        const float* src = X + (size_t)(brow + row) * IN_DIM;
        #pragma unroll
        for (int i = 0; i < 8; ++i) {
            f32x4 v = *reinterpret_cast<const f32x4*>(src + q * 4 + i * 64);
            const int byte = q * 8 + i * 128;            // bf16 byte offset
            const int dst  = row * 1024 + (((byte & ~15) ^ swz) | (byte & 8));
            u64 p = (u64)pack2bf(v.x, v.y) | ((u64)pack2bf(v.z, v.w) << 32);
            *reinterpret_cast<u64*>((char*)sA + dst) = p;
        }
    }
    __syncthreads();     // A published (also drains B(0),B(1) -> they're ready)

    // precomputed A lane addresses (per m); + h*64 literal per step
    int aaddr[2];
    #pragma unroll
    for (int m = 0; m < 2; ++m) {
        const int r = m * 16 + ll;
        aaddr[m] = r * 1024 + ((lh * 16) ^ ((r & 3) << 4));
    }

    // ---- K-loop: 16 half-steps, no barriers, per-wave pipeline ----------
    f32x4 acc[2][4] = {};

    #pragma unroll
    for (int h = 0; h < 16; ++h) {
        // retire B(h): outstanding before = {B(h+1)} or {B(h),B(h+1)}
        if (h < 15) { VMW4; } else { VMW0; }
        if (h < 14) loadB(h + 2, (h + 2) % 3);   // 2-deep lookahead
        asm volatile("" ::: "memory");

        bf16x8 a[2];
        #pragma unroll
        for (int m = 0; m < 2; ++m)
            a[m] = *reinterpret_cast<const bf16x8*>(
                (const char*)sA + aaddr[m] + h * 64);

        #pragma unroll
        for (int m = 0; m < 2; ++m)
            #pragma unroll
            for (int n = 0; n < 4; ++n)
                acc[m][n] = __builtin_amdgcn_mfma_f32_16x16x32_bf16(
                    a[m], b[h % 3][n], acc[m][n], 0, 0, 0);
    }

    #undef VMW4
    #undef VMW0

    // ---- epilogue -------------------------------------------------------
    #pragma unroll
    for (int n = 0; n < 4; ++n) {
        const int col = w * 64 + n * 16 + ll;
        const float bv = bias[col];
        #pragma unroll
        for (int m = 0; m < 2; ++m) {
            const int row0 = brow + m * 16 + lh * 4;
            #pragma unroll
            for (int r = 0; r < 4; ++r)
                out[(size_t)(row0 + r) * OUT_DIM + col] = acc[m][n][r] + bv;
        }
    }
}

// ---------------------------------------------------------------------------
extern "C" void kernel_launch(void* const* d_in, const int* in_sizes, int n_in,
                              void* d_out, int out_size, void* d_ws, size_t ws_size,
                              hipStream_t stream) {
    const float* x          = (const float*)d_in[0];
    const float* omega      = (const float*)d_in[1];
    const float* phi        = (const float*)d_in[2];
    const float* alpha      = (const float*)d_in[3];
    const float* alpha_bias = (const float*)d_in[4];
    const int*   layer_idx  = (const int*)d_in[5];
    const int*   num_layers = (const int*)d_in[6];
    float* out = (float*)d_out;

    const int M = in_sizes[0] / IN_DIM;   // 8192

    u16*   Wt   = (u16*)d_ws;                                  // 512KB
    float* bias = (float*)((char*)d_ws + 512 * 1024);          // 2KB

    synth_fused<<<256, 512, 0, stream>>>(omega, phi, alpha, alpha_bias,
                                         layer_idx, num_layers, Wt, bias);
    main_gemm<<<M / 32, 512, 0, stream>>>(x, Wt, bias, out, M);
}

// Round 9
// 24.515 us; speedup vs baseline: 1.2564x; 1.2564x over previous
//
#include <hip/hip_runtime.h>
#include <hip/hip_bf16.h>
#include <math.h>

#define IN_DIM   512
#define OUT_DIM  512
#define NK       192          // TOTAL_K
#define KF       384          // 2*TOTAL_K
#define XAVIER   0.04419417382415922f
#define BIAS_SCALE 0.02f

typedef __attribute__((ext_vector_type(8))) short bf16x8;
typedef __attribute__((ext_vector_type(4))) float f32x4;
typedef unsigned short u16;
typedef unsigned int   u32;
typedef unsigned long long u64;

__device__ inline u16 f2bf(float f) {
    __hip_bfloat16 h = __float2bfloat16(f);
    return *reinterpret_cast<u16*>(&h);
}
__device__ inline u32 pack2bf(float lo, float hi) {
    return (u32)f2bf(lo) | ((u32)f2bf(hi) << 16);
}
__device__ inline void gload_lds16(const void* g, void* l) {
    __builtin_amdgcn_global_load_lds(
        (const __attribute__((address_space(1))) void*)g,
        (__attribute__((address_space(3))) void*)l, 16, 0, 0);
}
// Native-rate sincos (revolutions). |arg| < ~50 rad here; err ~1e-6 << bf16 W quant.
__device__ inline void fsincos(float x, float& s, float& c) {
    float t = x * 0.15915494309189535f;   // 1/(2*pi)
    t -= floorf(t);
    s = __builtin_amdgcn_sinf(t);
    c = __builtin_amdgcn_cosf(t);
}

// ---------------------------------------------------------------------------
// Kernel 1: synthesis — byte-identical to the verified 24.1us version.
// ---------------------------------------------------------------------------
__global__ __launch_bounds__(512) void synth_fused(
    const float* __restrict__ omega, const float* __restrict__ phi,
    const float* __restrict__ alpha, const float* __restrict__ alpha_bias,
    const int* __restrict__ layer_idx, const int* __restrict__ num_layers,
    u16* __restrict__ Wt, float* __restrict__ bias)
{
    const int b   = blockIdx.x;
    const int tid = threadIdx.x;
    const float l = ((float)layer_idx[0] + 1.0f) / ((float)num_layers[0] + 1.0f);

    __shared__ u16 sV[32 * KF];   // 24KB
    __shared__ u16 sU[32 * KF];   // 24KB
    __shared__ float bsc[4];

    const int bi = b & 15, bj = b >> 4;
    const int i0 = bi * 32, j0 = bj * 32;

    #pragma unroll 4
    for (int q = 0; q < 12; ++q) {
        const int e  = q * 512 + tid;     // 0..6143
        const int rl = e / NK;
        const int k  = e - rl * NK;
        const int swz  = (rl & 7) << 4;
        const int base = rl * (KF * 2);
        const float om0 = omega[3*k], om1 = omega[3*k+1], om2 = omega[3*k+2];
        const float ph  = phi[k];
        {
            const float ii = (i0 + rl + 1.0f) * (1.0f / (IN_DIM + 1.0f));
            float s, c; fsincos(fmaf(ii, om0, fmaf(l, om2, ph)), s, c);
            *(u16*)((char*)sU + base + (((2*k)      ) ^ swz)) = f2bf(s);
            *(u16*)((char*)sU + base + (((2*k) + 384) ^ swz)) = f2bf(c);
        }
        {
            const float jj = (j0 + rl + 1.0f) * (1.0f / (OUT_DIM + 1.0f));
            float sv, cv; fsincos(jj * om1, sv, cv);
            const float as = alpha[k], ac = alpha[NK + k];
            *(u16*)((char*)sV + base + (((2*k)      ) ^ swz)) = f2bf((as*cv - ac*sv) * XAVIER);
            *(u16*)((char*)sV + base + (((2*k) + 384) ^ swz)) = f2bf((ac*cv + as*sv) * XAVIER);
        }
    }

    // bias partials: waves 4..7 (k-parallel, 128 threads per output)
    if (tid >= 256) {
        const int t2 = tid - 256;
        const int g  = t2 >> 7;
        const int k0 = t2 & 127;
        const int j  = 2*b + g;
        const float jj = (j + 1.0f) * (1.0f / (OUT_DIM + 1.0f));
        float bp = 0.0f;
        {
            float s, c;
            fsincos(fmaf(jj, omega[3*k0+1], fmaf(l, omega[3*k0+2], phi[k0])), s, c);
            bp = fmaf(alpha_bias[k0], s, fmaf(alpha_bias[NK + k0], c, bp));
        }
        if (k0 < 64) {
            const int k = k0 + 128;
            float s, c;
            fsincos(fmaf(jj, omega[3*k+1], fmaf(l, omega[3*k+2], phi[k])), s, c);
            bp = fmaf(alpha_bias[k], s, fmaf(alpha_bias[NK + k], c, bp));
        }
        #pragma unroll
        for (int off = 32; off > 0; off >>= 1)
            bp += __shfl_down(bp, off);
        if ((tid & 63) == 0) bsc[t2 >> 6] = bp;
    }
    __syncthreads();

    // 32x32x384 tile GEMM (waves 0..3) -> Wt
    if (tid < 256) {
        const int wave = tid >> 6, lane = tid & 63;
        const int wr = wave >> 1, wc = wave & 1;
        f32x4 acc = {};
        #pragma unroll
        for (int kk = 0; kk < KF / 32; ++kk) {
            const int kb = kk * 64 + (lane >> 4) * 16;
            const int ra = wr*16 + (lane & 15);
            const int rb = wc*16 + (lane & 15);
            bf16x8 a = *reinterpret_cast<const bf16x8*>(
                (const char*)sV + ra*768 + (kb ^ ((ra & 7) << 4)));
            bf16x8 bb = *reinterpret_cast<const bf16x8*>(
                (const char*)sU + rb*768 + (kb ^ ((rb & 7) << 4)));
            acc = __builtin_amdgcn_mfma_f32_16x16x32_bf16(a, bb, acc, 0, 0, 0);
        }
        const int row = j0 + wr*16 + (lane >> 4) * 4;   // out col j
        const int col = i0 + wc*16 + (lane & 15);       // in row i
        #pragma unroll
        for (int r = 0; r < 4; ++r)
            Wt[(size_t)(row + r) * IN_DIM + col] = f2bf(acc[r]);
    }
    if (tid == 256) bias[2*b    ] = (bsc[0] + bsc[1]) * BIAS_SCALE;
    if (tid == 257) bias[2*b + 1] = (bsc[2] + bsc[3]) * BIAS_SCALE;
}

// ---------------------------------------------------------------------------
// Kernel 2: out = x @ W + b.  Round-1's PROVEN pipeline, BN-split 512->256 so
// LDS = 2x32KB B + 2x4KB A = 72KB -> 2 BLOCKS PER CU (grid 512). Rationale:
// every 1-block/CU variant leaves the CU fully idle during the per-K-step
// vmcnt+barrier drain (r2 counters: 87% idle); m97's ladder hid exactly this
// drain via multi-block residency (m114 co-scheduling). Per-block structure,
// swizzles, chunk geometry (wave w stages exactly the rows it consumes),
// counted-vmcnt discipline all unchanged; x read 2x (irrelevant at our BW%).
// ---------------------------------------------------------------------------
__global__ __launch_bounds__(512) void main_gemm(
    const float* __restrict__ X, const u16* __restrict__ Wt,
    const float* __restrict__ bias, float* __restrict__ out, int M)
{
    __shared__ u16 sA[2][32 * 64];    // 2 x 4KB
    __shared__ u16 sB[2][256 * 64];   // 2 x 32KB

    const int tid  = threadIdx.x;
    const int w    = tid >> 6, lane = tid & 63;
    const int ll   = lane & 15, lh = lane >> 4;
    const int rowt = blockIdx.x >> 1;
    const int ch   = blockIdx.x & 1;          // column half
    const int brow = rowt * 32;
    const int jbase = ch * 256;
    const int ph2  = (blockIdx.x >> 3) & 7;   // K-phase stagger (neutral, kept)

    f32x4 acc[2][2] = {};

    const int bsrc  = ((lane & 7) * 16) ^ ((lane >> 3) << 4);
    const int bjrow = lane >> 3;
    const int arow = tid >> 4;            // 0..31
    const int akq  = tid & 15;            // 0..15
    const int adst = arow * 128 + ((akq * 8) ^ ((arow & 7) << 4));
    const size_t xoff = (size_t)(brow + arow) * IN_DIM + akq * 4;

    auto kof = [&](int s) -> int { return ((s + ph2) & 7) * 64; };

    // 32 chunks of 1KB (8 rows x 128B); wave w does chunks w*4..w*4+3 ->
    // stages exactly rows w*32..w*32+31, which it alone consumes.
    auto stageB = [&](int buf, int k0) {
        #pragma unroll
        for (int c = 0; c < 4; ++c) {
            const int ci = w * 4 + c;
            const int j  = jbase + ci * 8 + bjrow;
            gload_lds16((const char*)Wt + (size_t)j * (IN_DIM * 2) + k0 * 2 + bsrc,
                        (char*)&sB[buf][0] + ci * 1024);
        }
    };
    auto loadA = [&](int k0) -> f32x4 {
        return *reinterpret_cast<const f32x4*>(&X[xoff + k0]);
    };
    auto writeA = [&](int buf, f32x4 v) {
        u64 p = (u64)pack2bf(v.x, v.y) | ((u64)pack2bf(v.z, v.w) << 32);
        *reinterpret_cast<u64*>((char*)&sA[buf][0] + adst) = p;
    };
    auto compute = [&](int buf) {
        #pragma unroll
        for (int kk = 0; kk < 2; ++kk) {
            const int kb = kk * 64 + lh * 16;
            bf16x8 a[2], bb[2];
            #pragma unroll
            for (int m = 0; m < 2; ++m) {
                const int r = m*16 + ll;
                a[m] = *reinterpret_cast<const bf16x8*>(
                    (const char*)&sA[buf][0] + r*128 + (kb ^ ((r & 7) << 4)));
            }
            #pragma unroll
            for (int n = 0; n < 2; ++n) {
                const int jl = w*32 + n*16 + ll;
                bb[n] = *reinterpret_cast<const bf16x8*>(
                    (const char*)&sB[buf][0] + jl*128 + (kb ^ ((jl & 7) << 4)));
            }
            #pragma unroll
            for (int m = 0; m < 2; ++m)
                #pragma unroll
                for (int n = 0; n < 2; ++n)
                    acc[m][n] = __builtin_amdgcn_mfma_f32_16x16x32_bf16(
                        a[m], bb[n], acc[m][n], 0, 0, 0);
        }
    };

    #define VMW(n)  asm volatile("s_waitcnt vmcnt(" #n ")" ::: "memory")
    #define LGKM0   asm volatile("s_waitcnt lgkmcnt(0)" ::: "memory")
    #define BARRIER do { __builtin_amdgcn_s_barrier(); \
                         asm volatile("" ::: "memory"); } while (0)

    // prologue: stage steps 0 and 1 -------------------------------------
    {
        f32x4 av = loadA(kof(0));     // 1 load (oldest)
        stageB(0, kof(0));            // +4
        VMW(4);               // retires A(0); 4 B(0) in flight
        writeA(0, av);
        av = loadA(kof(1));           // +1
        stageB(1, kof(1));            // +4 -> 9
        VMW(4);               // retires 4 B(0) + A(1); 4 B(1) in flight
        writeA(1, av);
        LGKM0;
        BARRIER;              // B(0)+A(0)+A(1) published
    }

    #pragma unroll
    for (int t = 0; t < 8; ++t) {
        compute(t & 1);       // step t (k=kof(t)) guaranteed by prior barrier
        BARRIER;              // buf[t&1] free to overwrite
        if (t < 6) {
            f32x4 av = loadA(kof(t + 2));      // +1
            stageB(t & 1, kof(t + 2));         // +4 -> 9 outstanding
            VMW(4);           // retires 4 B(t+1) + A(t+2); 4 B(t+2) in flight
            writeA(t & 1, av);
        } else if (t == 6) {
            VMW(0);           // drain B(7)
        }
        LGKM0;
        BARRIER;              // publish B(t+1) (+ A(t+2))
    }

    #undef VMW
    #undef LGKM0
    #undef BARRIER

    // epilogue ------------------------------------------------------------
    #pragma unroll
    for (int n = 0; n < 2; ++n) {
        const int col = jbase + w*32 + n*16 + ll;
        const float bv = bias[col];
        #pragma unroll
        for (int m = 0; m < 2; ++m) {
            const int row0 = brow + m*16 + lh * 4;
            #pragma unroll
            for (int r = 0; r < 4; ++r)
                out[(size_t)(row0 + r) * OUT_DIM + col] = acc[m][n][r] + bv;
        }
    }
}

// ---------------------------------------------------------------------------
extern "C" void kernel_launch(void* const* d_in, const int* in_sizes, int n_in,
                              void* d_out, int out_size, void* d_ws, size_t ws_size,
                              hipStream_t stream) {
    const float* x          = (const float*)d_in[0];
    const float* omega      = (const float*)d_in[1];
    const float* phi        = (const float*)d_in[2];
    const float* alpha      = (const float*)d_in[3];
    const float* alpha_bias = (const float*)d_in[4];
    const int*   layer_idx  = (const int*)d_in[5];
    const int*   num_layers = (const int*)d_in[6];
    float* out = (float*)d_out;

    const int M = in_sizes[0] / IN_DIM;   // 8192

    u16*   Wt   = (u16*)d_ws;                                  // 512KB
    float* bias = (float*)((char*)d_ws + 512 * 1024);          // 2KB

    synth_fused<<<256, 512, 0, stream>>>(omega, phi, alpha, alpha_bias,
                                         layer_idx, num_layers, Wt, bias);
    main_gemm<<<(M / 32) * 2, 512, 0, stream>>>(x, Wt, bias, out, M);
}